// Round 6
// baseline (191.621 us; speedup 1.0000x reference)
//
#include <hip/hip_runtime.h>
#include <stdint.h>

#define DIM 1024
#define GLOBAL_AS __attribute__((address_space(1)))
#define LDS_AS __attribute__((address_space(3)))

typedef short bf16x8 __attribute__((ext_vector_type(8)));
typedef float f32x4 __attribute__((ext_vector_type(4)));
typedef unsigned short u16x4 __attribute__((ext_vector_type(4)));

// deg-4 Taylor via depth-2: R = I + A + A2/2 + (C3*A + C4*A2)*A2
#define C3f 0.16666667f
#define C4f 0.041666668f

__device__ __forceinline__ unsigned short f32_to_bf16(float f) {
    union { float f; uint32_t u; } v; v.f = f;
    uint32_t u = v.u;
    u += 0x7FFFu + ((u >> 16) & 1u);   // round-to-nearest-even
    return (unsigned short)(u >> 16);
}
__device__ __forceinline__ float bf16_to_f32(unsigned short u) {
    union { uint32_t u; float f; } v; v.u = ((uint32_t)u) << 16;
    return v.f;
}

// async global->LDS, 16B per lane; LDS dst = wave-uniform base + lane*16.
__device__ __forceinline__ void async16(const void* g, void* l) {
    __builtin_amdgcn_global_load_lds((GLOBAL_AS const void*)g,
                                     (LDS_AS void*)l, 16, 0, 0);
}

// Coalesced A = W - W^T via 32x32 LDS tile transpose.
// Ab = bf16(A) (A-operand), G = bf16(-A) = bf16(A^T) (B-operand).
__global__ __launch_bounds__(256) void k_init(const float* __restrict__ W,
        unsigned short* __restrict__ Ab, unsigned short* __restrict__ G) {
    __shared__ float t2[32][33];
    int i0 = (blockIdx.x & 31) * 32, j0 = (blockIdx.x >> 5) * 32;
    int tx = threadIdx.x & 31, ty = threadIdx.x >> 5;
    float t1[4];
    #pragma unroll
    for (int p = 0; p < 4; p++) {
        int r = p * 8 + ty;
        t1[p] = W[(i0 + r) * DIM + j0 + tx];            // coalesced
        t2[r][tx] = W[(j0 + r) * DIM + i0 + tx];        // coalesced
    }
    __syncthreads();
    #pragma unroll
    for (int p = 0; p < 4; p++) {
        int r = p * 8 + ty;
        float a = t1[p] - t2[tx][r];                    // W[i][j] - W[j][i]
        int gi = (i0 + r) * DIM + j0 + tx;
        Ab[gi] = f32_to_bf16(a);
        G[gi]  = f32_to_bf16(-a);
    }
}

// Split-K GEMM round: out_partial[sp] = P[m-panel] x Qt[n-panel]^T over
// K = [sp*256, sp*256+256). 1024 blocks = 256 tiles x 4 splits; ONE staging
// round (BK=256), no K-chain of barrier drains. Partials are fp32.
// R5 rationale: the chained small GEMMs at 256 blocks were ~38 us each
// (m102 shape curve: N=1024 -> ~90 TF for this structure, parallelism-starved).
// Split-K x4 gives 1024 blocks and a single round -> ~4x less serial latency.
__device__ __forceinline__ void gemm_split(const unsigned short* __restrict__ P,
        const unsigned short* __restrict__ Qt, float* __restrict__ outp) {
    __shared__ unsigned short lA[64 * 256];   // 32 KB
    __shared__ unsigned short lB[64 * 256];   // 32 KB
    int bid = blockIdx.x, tid = threadIdx.x;
    int sp = bid >> 8, t = bid & 255;
    int m0 = (t & 15) * 64, n0 = (t >> 4) * 64, kb = sp * 256;
    int lane = tid & 63, w = tid >> 6;
    int wr = w >> 1, wc = w & 1;
    int rr = lane & 15, ko = lane >> 4;
    f32x4 acc[2][2] = {};
    #pragma unroll
    for (int i = 0; i < 8; i++) {
        int l = i * 256 + tid;                // 0..2047 = 64 rows x 32 chunks
        int r = l >> 5, cst = l & 31;
        int cd = cst ^ (r & 7);
        async16(&P[(m0 + r) * DIM + kb + cd * 8], &lA[l * 8]);
        async16(&Qt[(n0 + r) * DIM + kb + cd * 8], &lB[l * 8]);
    }
    __syncthreads();
    #pragma unroll
    for (int s = 0; s < 8; s++) {
        int cd = s * 4 + ko;
        bf16x8 af[2], bq[2];
        #pragma unroll
        for (int mi = 0; mi < 2; mi++) {
            int ra = wr * 32 + mi * 16 + rr;
            af[mi] = *(const bf16x8*)&lA[ra * 256 + ((cd ^ (ra & 7)) * 8)];
        }
        #pragma unroll
        for (int ni = 0; ni < 2; ni++) {
            int rb = wc * 32 + ni * 16 + rr;
            bq[ni] = *(const bf16x8*)&lB[rb * 256 + ((cd ^ (rb & 7)) * 8)];
        }
        #pragma unroll
        for (int mi = 0; mi < 2; mi++)
            #pragma unroll
            for (int ni = 0; ni < 2; ni++)
                acc[mi][ni] = __builtin_amdgcn_mfma_f32_16x16x32_bf16(
                    af[mi], bq[ni], acc[mi][ni], 0, 0, 0);
    }
    float* out = outp + (size_t)sp * DIM * DIM;
    #pragma unroll
    for (int mi = 0; mi < 2; mi++)
        #pragma unroll
        for (int ni = 0; ni < 2; ni++)
            #pragma unroll
            for (int q = 0; q < 4; q++) {
                int rl = wr * 32 + mi * 16 + ko * 4 + q;
                int cl = wc * 32 + ni * 16 + rr;
                out[(m0 + rl) * DIM + n0 + cl] = acc[mi][ni][q];
            }
}

__global__ __launch_bounds__(256) void k_g1s(
        const unsigned short* __restrict__ Ab, const unsigned short* __restrict__ G,
        float* __restrict__ A2p) {
    gemm_split(Ab, G, A2p);                   // A2 = A*A (G = -A = A^T rows)
}

__global__ __launch_bounds__(256) void k_g2s(
        const unsigned short* __restrict__ Pb, const unsigned short* __restrict__ A2b,
        float* __restrict__ Tp) {
    gemm_split(Pb, A2b, Tp);                  // T = P*A2 (A2 symmetric -> Qt=A2b)
}

// Combine 1: A2 = sum of 4 partials; A2b = bf16(A2); Pb = bf16(C3*A + C4*A2).
__global__ __launch_bounds__(256) void k_c1(const float* __restrict__ A2p,
        const unsigned short* __restrict__ Ab,
        unsigned short* __restrict__ A2b, unsigned short* __restrict__ Pb) {
    int id = blockIdx.x * 256 + threadIdx.x;          // 262144 f32x4 units
    const f32x4* p = (const f32x4*)A2p;
    f32x4 v = p[id] + p[id + 262144] + p[id + 524288] + p[id + 786432];
    u16x4 a4 = *(const u16x4*)&Ab[id * 4];
    u16x4 o1, o2;
    #pragma unroll
    for (int q = 0; q < 4; q++) {
        float a = bf16_to_f32(a4[q]);
        o1[q] = f32_to_bf16(v[q]);
        o2[q] = f32_to_bf16(C3f * a + C4f * v[q]);
    }
    *(u16x4*)&A2b[id * 4] = o1;
    *(u16x4*)&Pb[id * 4] = o2;
}

// Combine 2: R = sumTp + I + A + A2/2; emit R^T bf16 via 32x32 LDS transpose.
__global__ __launch_bounds__(256) void k_c2(const float* __restrict__ Tp,
        const unsigned short* __restrict__ Ab,
        const unsigned short* __restrict__ A2b,
        unsigned short* __restrict__ Rtb) {
    __shared__ float t2[32][33];
    int i0 = (blockIdx.x & 31) * 32, j0 = (blockIdx.x >> 5) * 32;
    int tx = threadIdx.x & 31, ty = threadIdx.x >> 5;
    #pragma unroll
    for (int p = 0; p < 4; p++) {
        int r = p * 8 + ty;
        int gi = (i0 + r) * DIM + j0 + tx;            // coalesced along tx
        float v = Tp[gi] + Tp[gi + 1048576] + Tp[gi + 2097152] + Tp[gi + 3145728];
        v += bf16_to_f32(Ab[gi]) + 0.5f * bf16_to_f32(A2b[gi]);
        if (i0 + r == j0 + tx) v += 1.0f;
        t2[r][tx] = v;                                // t2[ii][jj] = R(i0+ii, j0+jj)
    }
    __syncthreads();
    #pragma unroll
    for (int p = 0; p < 4; p++) {
        int r = p * 8 + ty;
        // Rt[j0+r][i0+tx] = R[i0+tx][j0+r] = t2[tx][r]; coalesced store.
        Rtb[(j0 + r) * DIM + i0 + tx] = f32_to_bf16(t2[tx][r]);
    }
}

// Out(16384x1024) = X(fp32) @ R, R^T row-major bf16 (Rtb).
// R5 change: read X fp32 DIRECTLY (no Xb round trip: saves 96 MB + a whole
// ~40 us convert kernel). X is reg-staged: f32x4 loads -> bf16 convert ->
// swizzled ds_write_b128 (same c^(r&7) involution the ds_read expects).
// B (Rtb) keeps global_load_lds. 128x128 tiles, BK=64, 1024 blocks.
__global__ __launch_bounds__(256, 3) void k_biggemm(
        const float* __restrict__ X,
        const unsigned short* __restrict__ Rtb,
        float* __restrict__ Out) {
    __shared__ unsigned short lX[128 * 64];   // 16 KB
    __shared__ unsigned short lB[128 * 64];   // 16 KB
    int tid = threadIdx.x;
    int bid = blockIdx.x;
    int m0 = (bid & 127) * 128, n0 = (bid >> 7) * 128;
    int lane = tid & 63, w = tid >> 6;
    int wr = w >> 1, wc = w & 1;
    int rr = lane & 15, ko = lane >> 4;
    f32x4 acc[4][4] = {};
    for (int kb = 0; kb < DIM; kb += 64) {
        // ---- stage X (fp32 -> bf16, reg path): 4 LDS chunks/thread ----
        f32x4 xv[8];
        #pragma unroll
        for (int i = 0; i < 4; i++) {
            int l = i * 256 + tid;            // 1024 chunks = 128 rows x 8
            int r = l >> 3, c = l & 7;
            const float* src = &X[(size_t)(m0 + r) * DIM + kb + ((c ^ (r & 7)) * 8)];
            xv[2 * i]     = *(const f32x4*)src;
            xv[2 * i + 1] = *(const f32x4*)(src + 4);
        }
        // ---- stage B (bf16 direct-to-LDS) ----
        #pragma unroll
        for (int i = 0; i < 4; i++) {
            int l = i * 256 + tid;
            int r = l >> 3, cst = l & 7;
            int cd = cst ^ (r & 7);
            async16(&Rtb[(n0 + r) * DIM + kb + cd * 8], &lB[l * 8]);
        }
        // ---- convert + swizzled LDS write ----
        #pragma unroll
        for (int i = 0; i < 4; i++) {
            int l = i * 256 + tid;
            int r = l >> 3, c = l & 7;
            unsigned short o[8];
            #pragma unroll
            for (int q = 0; q < 4; q++) {
                o[q]     = f32_to_bf16(xv[2 * i][q]);
                o[4 + q] = f32_to_bf16(xv[2 * i + 1][q]);
            }
            *(bf16x8*)&lX[r * 64 + c * 8] = *(bf16x8*)o;
        }
        __syncthreads();
        #pragma unroll
        for (int s = 0; s < 2; s++) {
            int cd = s * 4 + ko;
            bf16x8 af[4], bq[4];
            #pragma unroll
            for (int mi = 0; mi < 4; mi++) {
                int ra = wr * 64 + mi * 16 + rr;
                af[mi] = *(const bf16x8*)&lX[ra * 64 + ((cd ^ (ra & 7)) * 8)];
            }
            #pragma unroll
            for (int ni = 0; ni < 4; ni++) {
                int rb = wc * 64 + ni * 16 + rr;
                bq[ni] = *(const bf16x8*)&lB[rb * 64 + ((cd ^ (rb & 7)) * 8)];
            }
            #pragma unroll
            for (int mi = 0; mi < 4; mi++)
                #pragma unroll
                for (int ni = 0; ni < 4; ni++)
                    acc[mi][ni] = __builtin_amdgcn_mfma_f32_16x16x32_bf16(
                        af[mi], bq[ni], acc[mi][ni], 0, 0, 0);
        }
        __syncthreads();
    }
    #pragma unroll
    for (int mi = 0; mi < 4; mi++)
        #pragma unroll
        for (int ni = 0; ni < 4; ni++)
            #pragma unroll
            for (int q = 0; q < 4; q++) {
                int row = m0 + wr * 64 + mi * 16 + ko * 4 + q;
                int col = n0 + wc * 64 + ni * 16 + rr;
                Out[(size_t)row * DIM + col] = acc[mi][ni][q];
            }
}

extern "C" void kernel_launch(void* const* d_in, const int* in_sizes, int n_in,
                              void* d_out, int out_size, void* d_ws, size_t ws_size,
                              hipStream_t stream) {
    const float* X = (const float*)d_in[0];        // 4*4096*1024 fp32
    const float* W = (const float*)d_in[1];        // 1024*1024 fp32
    float* Out = (float*)d_out;                    // 16384*1024 fp32
    char* ws = (char*)d_ws;
    const size_t MB = 1u << 20;
    unsigned short* Ab  = (unsigned short*)(ws + 0 * MB);
    unsigned short* G   = (unsigned short*)(ws + 2 * MB);
    unsigned short* A2b = (unsigned short*)(ws + 4 * MB);
    unsigned short* Pb  = (unsigned short*)(ws + 6 * MB);
    unsigned short* Rtb = (unsigned short*)(ws + 8 * MB);
    float* A2p = (float*)(ws + 10 * MB);           // 4 x 4 MB fp32 partials
    float* Tp  = (float*)(ws + 26 * MB);           // 4 x 4 MB fp32 partials

    k_init<<<1024, 256, 0, stream>>>(W, Ab, G);
    // A2 partials (split-K x4), then combine -> A2b, Pb
    k_g1s<<<1024, 256, 0, stream>>>(Ab, G, A2p);
    k_c1<<<1024, 256, 0, stream>>>(A2p, Ab, A2b, Pb);
    // T partials (split-K x4), then combine -> R^T bf16
    k_g2s<<<1024, 256, 0, stream>>>(Pb, A2b, Tp);
    k_c2<<<1024, 256, 0, stream>>>(Tp, Ab, A2b, Rtb);
    // big GEMM reads X fp32 directly
    k_biggemm<<<1024, 256, 0, stream>>>(X, Rtb, Out);
}